// Round 1
// baseline (1528.167 us; speedup 1.0000x reference)
//
#include <hip/hip_runtime.h>
#include <math.h>

#define TT 2048
#define BB 32
#define EE 512
#define NN 512

// ---------------------------------------------------------------------------
// padding_mask dtype detector: int32 0/1 words stay <=1; byte-bool rows are
// monotonic so any packed word is 0x01000000/0x01010000/0x01010101/... (>1).
__global__ void detect_mask_kernel(const unsigned* __restrict__ pm, int* __restrict__ flag) {
    __shared__ int s[256];
    const int l = threadIdx.x;
    int bad = 0;
    for (int i = l; i < BB * TT; i += 256) bad |= (pm[i] > 1u);
    s[l] = bad;
    __syncthreads();
    for (int st = 128; st > 0; st >>= 1) { if (l < st) s[l] |= s[l + st]; __syncthreads(); }
    if (l == 0) *flag = s[0];
}

__device__ __forceinline__ int pad_at(const void* pm, int idx, int isByte) {
    return isByte ? (int)(((const unsigned char*)pm)[idx] != 0)
                  : (int)(((const int*)pm)[idx] != 0);
}

// ---------------------------------------------------------------------------
// padding_start[b] = count of not-pad = lengths[b]
__global__ void compute_ps_kernel(const void* __restrict__ pm, const int* __restrict__ flag,
                                  int* __restrict__ ps) {
    __shared__ int s[256];
    const int b = blockIdx.x, l = threadIdx.x;
    const int isByte = *flag;
    int cnt = 0;
    for (int t = l; t < TT; t += 256) cnt += (pad_at(pm, b * TT + t, isByte) == 0);
    s[l] = cnt;
    __syncthreads();
    for (int st = 128; st > 0; st >>= 1) { if (l < st) s[l] += s[l + st]; __syncthreads(); }
    if (l == 0) ps[b] = s[0];
}

// ---------------------------------------------------------------------------
// Fused fp32 GEMM + relu + dot(v) + sigmoid + mask.
// One block per t (32 rows = all b). BM=32 rows x full N=512, BK=8.
// 256 threads: ty in [0,8) -> 4 rows each, tx in [0,32) -> 16 cols each.
__global__ __launch_bounds__(256, 2) void gemm_weight_kernel(
    const float* __restrict__ x, const void* __restrict__ pm, const int* __restrict__ flag,
    const float* __restrict__ W, const float* __restrict__ bias,
    const float* __restrict__ v, const float* __restrict__ vb,
    float* __restrict__ weight) {
    __shared__ float Bs[8][512];
    __shared__ float As[8][36];   // [k][row], padded to 36 for bank spread + f4 align
    __shared__ float bias_s[512], v_s[512];
    const int l = threadIdx.x;
    const int tx = l & 31, ty = l >> 5;
    const int t = blockIdx.x;
    for (int i = l; i < 512; i += 256) { bias_s[i] = bias[i]; v_s[i] = v[i]; }

    float acc[4][16];
#pragma unroll
    for (int i = 0; i < 4; ++i)
#pragma unroll
        for (int j = 0; j < 16; ++j) acc[i][j] = 0.f;

    const float* xblk = x + (size_t)t * (BB * EE);  // rows r = t*32 + b are contiguous
    const int arow = l >> 3, akk = l & 7;           // 32 rows x 8 k each staged by one lane

    for (int k0 = 0; k0 < EE; k0 += 8) {
        __syncthreads();
        As[akk][arow] = xblk[arow * EE + k0 + akk];
#pragma unroll
        for (int j = 0; j < 4; ++j) {
            const int idx = l + j * 256;     // 0..1023 -> 8 k-rows x 128 float4
            const int kk = idx >> 7, n4 = idx & 127;
            *(float4*)&Bs[kk][n4 * 4] = *(const float4*)&W[(size_t)(k0 + kk) * NN + n4 * 4];
        }
        __syncthreads();
#pragma unroll
        for (int k = 0; k < 8; ++k) {
            const float4 a4 = *(const float4*)&As[k][ty * 4];
            const float4 b0 = *(const float4*)&Bs[k][tx * 16 + 0];
            const float4 b1 = *(const float4*)&Bs[k][tx * 16 + 4];
            const float4 b2 = *(const float4*)&Bs[k][tx * 16 + 8];
            const float4 b3 = *(const float4*)&Bs[k][tx * 16 + 12];
            const float a[4] = {a4.x, a4.y, a4.z, a4.w};
            const float bv[16] = {b0.x, b0.y, b0.z, b0.w, b1.x, b1.y, b1.z, b1.w,
                                  b2.x, b2.y, b2.z, b2.w, b3.x, b3.y, b3.z, b3.w};
#pragma unroll
            for (int i = 0; i < 4; ++i)
#pragma unroll
                for (int j = 0; j < 16; ++j) acc[i][j] = fmaf(a[i], bv[j], acc[i][j]);
        }
    }
    // epilogue: relu, dot with v over this thread's 16 cols, butterfly over tx
    float rsum[4] = {0.f, 0.f, 0.f, 0.f};
#pragma unroll
    for (int i = 0; i < 4; ++i) {
#pragma unroll
        for (int j = 0; j < 16; ++j) {
            const int n = tx * 16 + j;
            float h = fmaxf(acc[i][j] + bias_s[n], 0.f);
            rsum[i] = fmaf(h, v_s[n], rsum[i]);
        }
    }
#pragma unroll
    for (int m = 16; m >= 1; m >>= 1) {
#pragma unroll
        for (int i = 0; i < 4; ++i) rsum[i] += __shfl_xor(rsum[i], m, 64);
    }
    if (tx == 0) {
        const int isByte = *flag;
        const float vbias = *vb;
#pragma unroll
        for (int i = 0; i < 4; ++i) {
            const int b = ty * 4 + i;
            const float lg = rsum[i] + vbias;
            const float wg = 1.0f / (1.0f + expf(-lg));
            weight[t * BB + b] = pad_at(pm, b * TT + t, isByte) ? 0.f : wg;
        }
    }
}

// ---------------------------------------------------------------------------
// Sequential scalar scan per batch (must replicate reference's per-step fp32
// rounding exactly: cur = prev + w, minus exact 1.0 on fire).
// Emits per-t coefficient cc[] and per-frame records (t_first, t_last,
// first_coeff, scale) in compacted output order.
__global__ void cif_scan_kernel(const float* __restrict__ weight, const int* __restrict__ ps_arr,
                                float* __restrict__ cc, float4* __restrict__ recs,
                                int* __restrict__ nfr, float* __restrict__ out_q,
                                float* __restrict__ out_marks) {
    const int b = threadIdx.x;
    if (b >= BB) return;
    const int ps = ps_arr[b];
    float prev_w = 0.f, qsum = 0.f;
    int m = 0, t_first = 0;
    float fc = 0.f;
    for (int t = 0; t < TT; ++t) {
        const float w = weight[t * BB + b];
        qsum += w;
        if (t == 0) fc = w;  // frame 0 opens at t=0 with interior coeff
        float mark = 0.f;
        const bool fired = (prev_w + w >= 1.0f);   // invariant: prev_w < 1, so never fires where w==0
        const float remained = 1.0f - prev_w;
        if (fired) {
            cc[t * BB + b] = remained;             // closing coeff of frame m
            recs[b * TT + m] = make_float4(__int_as_float(t_first), __int_as_float(t), fc, 1.0f);
            mark = 1.f;
            ++m;
            t_first = t;                           // this t also opens frame m+1
            fc = w - remained;                     // with coeff cur_w
            prev_w = w - remained;
        } else {
            cc[t * BB + b] = w;
            prev_w += w;
        }
        if (t == ps) {                             // tail: cur_w = prev_w, cur_s spans [t_first, ps-1]
            if (prev_w > 0.6f) {
                recs[b * TT + m] = make_float4(__int_as_float(t_first), __int_as_float(t - 1),
                                               fc, 1.0f / (prev_w + 1e-10f));
                mark = 1.f;
                ++m;
            }
        }
        out_marks[b * TT + t] = mark;
    }
    out_q[b] = qsum;
    nfr[b] = m;
}

// ---------------------------------------------------------------------------
// Parallel frame materialization: block (j, b) -> compacted slot j of batch b.
// frame = scale * sum_t coeff(t) * x[t, b, :], short window (typ. 2-4 steps).
__global__ __launch_bounds__(128) void cif_out_kernel(
    const float* __restrict__ x, const float* __restrict__ cc,
    const float4* __restrict__ recs, const int* __restrict__ nfr,
    float* __restrict__ out_cif, float* __restrict__ out_mask) {
    const int j = blockIdx.x, b = blockIdx.y;
    const int l = threadIdx.x;
    const int m = nfr[b];
    float4 acc = make_float4(0.f, 0.f, 0.f, 0.f);
    const size_t obase = ((size_t)b * TT + j) * EE + l * 4;
    if (j < m) {
        const float4 r = recs[b * TT + j];
        const int t0 = __float_as_int(r.x);
        const int t1 = __float_as_int(r.y);
        const float fcoef = r.z, scale = r.w;
        for (int t = t0; t <= t1; ++t) {
            const float coeff = (t == t0) ? fcoef : cc[t * BB + b];
            const float4 xv = *(const float4*)&x[((size_t)t * BB + b) * EE + l * 4];
            acc.x = fmaf(coeff, xv.x, acc.x);
            acc.y = fmaf(coeff, xv.y, acc.y);
            acc.z = fmaf(coeff, xv.z, acc.z);
            acc.w = fmaf(coeff, xv.w, acc.w);
        }
        acc.x *= scale; acc.y *= scale; acc.z *= scale; acc.w *= scale;
        if (l == 0) out_mask[b * TT + j] = 1.f;
    } else {
        if (l == 0) out_mask[b * TT + j] = 0.f;
    }
    *(float4*)&out_cif[obase] = acc;
}

// ---------------------------------------------------------------------------
extern "C" void kernel_launch(void* const* d_in, const int* in_sizes, int n_in,
                              void* d_out, int out_size, void* d_ws, size_t ws_size,
                              hipStream_t stream) {
    const float* x    = (const float*)d_in[0];   // (T, B, E)
    const void*  pm   = d_in[1];                 // (B, T) bool -> int32 or bytes (detected)
    const float* W    = (const float*)d_in[2];   // (E, N)
    const float* bias = (const float*)d_in[3];   // (N,)
    const float* v    = (const float*)d_in[4];   // (N, 1)
    const float* vb   = (const float*)d_in[5];   // (1,)

    float* ws     = (float*)d_ws;
    float* weight = ws;                                   // TT*BB
    float* cc     = ws + TT * BB;                         // TT*BB
    float4* recs  = (float4*)(ws + 2 * TT * BB);          // BB*TT float4
    int* nfr      = (int*)(ws + 2 * TT * BB + 4 * BB * TT);
    int* ps       = nfr + BB;
    int* flag     = ps + BB;

    float* out_cif   = (float*)d_out;                     // (B, T, E)
    float* out_mask  = out_cif + (size_t)BB * TT * EE;    // (B, T)
    float* out_q     = out_mask + (size_t)BB * TT;        // (B,)
    float* out_marks = out_q + BB;                        // (B, T)

    detect_mask_kernel<<<1, 256, 0, stream>>>((const unsigned*)pm, flag);
    compute_ps_kernel<<<BB, 256, 0, stream>>>(pm, flag, ps);
    gemm_weight_kernel<<<TT, 256, 0, stream>>>(x, pm, flag, W, bias, v, vb, weight);
    cif_scan_kernel<<<1, 64, 0, stream>>>(weight, ps, cc, recs, nfr, out_q, out_marks);
    cif_out_kernel<<<dim3(TT, BB), 128, 0, stream>>>(x, cc, recs, nfr, out_cif, out_mask);
}

// Round 2
// 1072.194 us; speedup vs baseline: 1.4253x; 1.4253x over previous
//
#include <hip/hip_runtime.h>
#include <math.h>

#define TT 2048
#define BB 32
#define EE 512
#define NN 512

// ---------------------------------------------------------------------------
// padding_mask dtype detector: int32 0/1 words stay <=1; byte-bool rows are
// monotonic so any packed word is 0x01000000/0x01010000/0x01010101/... (>1).
__global__ void detect_mask_kernel(const unsigned* __restrict__ pm, int* __restrict__ flag) {
    __shared__ int s[256];
    const int l = threadIdx.x;
    int bad = 0;
    for (int i = l; i < BB * TT; i += 256) bad |= (pm[i] > 1u);
    s[l] = bad;
    __syncthreads();
    for (int st = 128; st > 0; st >>= 1) { if (l < st) s[l] |= s[l + st]; __syncthreads(); }
    if (l == 0) *flag = s[0];
}

__device__ __forceinline__ int pad_at(const void* pm, int idx, int isByte) {
    return isByte ? (int)(((const unsigned char*)pm)[idx] != 0)
                  : (int)(((const int*)pm)[idx] != 0);
}

// ---------------------------------------------------------------------------
// padding_start[b] = count of not-pad = lengths[b]
__global__ void compute_ps_kernel(const void* __restrict__ pm, const int* __restrict__ flag,
                                  int* __restrict__ ps) {
    __shared__ int s[256];
    const int b = blockIdx.x, l = threadIdx.x;
    const int isByte = *flag;
    int cnt = 0;
    for (int t = l; t < TT; t += 256) cnt += (pad_at(pm, b * TT + t, isByte) == 0);
    s[l] = cnt;
    __syncthreads();
    for (int st = 128; st > 0; st >>= 1) { if (l < st) s[l] += s[l + st]; __syncthreads(); }
    if (l == 0) ps[b] = s[0];
}

// ---------------------------------------------------------------------------
// Fused fp32 GEMM + relu + dot(v) + sigmoid + mask.
// One block per t (32 rows = all b). BM=32 rows x full N=512, BK=8.
// 256 threads: ty in [0,8) -> 4 rows each, tx in [0,32) -> 16 cols each.
// Writes weight in b-major layout (weight_bt[b*TT+t]) for the scan.
__global__ __launch_bounds__(256, 2) void gemm_weight_kernel(
    const float* __restrict__ x, const void* __restrict__ pm, const int* __restrict__ flag,
    const float* __restrict__ W, const float* __restrict__ bias,
    const float* __restrict__ v, const float* __restrict__ vb,
    float* __restrict__ weight_bt) {
    __shared__ float Bs[8][512];
    __shared__ float As[8][36];   // [k][row], padded to 36 for bank spread + f4 align
    __shared__ float bias_s[512], v_s[512];
    const int l = threadIdx.x;
    const int tx = l & 31, ty = l >> 5;
    const int t = blockIdx.x;
    for (int i = l; i < 512; i += 256) { bias_s[i] = bias[i]; v_s[i] = v[i]; }

    float acc[4][16];
#pragma unroll
    for (int i = 0; i < 4; ++i)
#pragma unroll
        for (int j = 0; j < 16; ++j) acc[i][j] = 0.f;

    const float* xblk = x + (size_t)t * (BB * EE);  // rows r = t*32 + b are contiguous
    const int arow = l >> 3, akk = l & 7;           // 32 rows x 8 k each staged by one lane

    for (int k0 = 0; k0 < EE; k0 += 8) {
        __syncthreads();
        As[akk][arow] = xblk[arow * EE + k0 + akk];
#pragma unroll
        for (int j = 0; j < 4; ++j) {
            const int idx = l + j * 256;     // 0..1023 -> 8 k-rows x 128 float4
            const int kk = idx >> 7, n4 = idx & 127;
            *(float4*)&Bs[kk][n4 * 4] = *(const float4*)&W[(size_t)(k0 + kk) * NN + n4 * 4];
        }
        __syncthreads();
#pragma unroll
        for (int k = 0; k < 8; ++k) {
            const float4 a4 = *(const float4*)&As[k][ty * 4];
            const float4 b0 = *(const float4*)&Bs[k][tx * 16 + 0];
            const float4 b1 = *(const float4*)&Bs[k][tx * 16 + 4];
            const float4 b2 = *(const float4*)&Bs[k][tx * 16 + 8];
            const float4 b3 = *(const float4*)&Bs[k][tx * 16 + 12];
            const float a[4] = {a4.x, a4.y, a4.z, a4.w};
            const float bv[16] = {b0.x, b0.y, b0.z, b0.w, b1.x, b1.y, b1.z, b1.w,
                                  b2.x, b2.y, b2.z, b2.w, b3.x, b3.y, b3.z, b3.w};
#pragma unroll
            for (int i = 0; i < 4; ++i)
#pragma unroll
                for (int j = 0; j < 16; ++j) acc[i][j] = fmaf(a[i], bv[j], acc[i][j]);
        }
    }
    // epilogue: relu, dot with v over this thread's 16 cols, butterfly over tx
    float rsum[4] = {0.f, 0.f, 0.f, 0.f};
#pragma unroll
    for (int i = 0; i < 4; ++i) {
#pragma unroll
        for (int j = 0; j < 16; ++j) {
            const int n = tx * 16 + j;
            float h = fmaxf(acc[i][j] + bias_s[n], 0.f);
            rsum[i] = fmaf(h, v_s[n], rsum[i]);
        }
    }
#pragma unroll
    for (int m = 16; m >= 1; m >>= 1) {
#pragma unroll
        for (int i = 0; i < 4; ++i) rsum[i] += __shfl_xor(rsum[i], m, 64);
    }
    if (tx == 0) {
        const int isByte = *flag;
        const float vbias = *vb;
#pragma unroll
        for (int i = 0; i < 4; ++i) {
            const int b = ty * 4 + i;
            const float lg = rsum[i] + vbias;
            const float wg = 1.0f / (1.0f + expf(-lg));
            weight_bt[(size_t)b * TT + t] = pad_at(pm, b * TT + t, isByte) ? 0.f : wg;
        }
    }
}

// ---------------------------------------------------------------------------
// Sequential scalar scan, one block per batch. Weights staged through LDS in
// 512-step chunks (coalesced float4); lane 0 runs the serial fp32 recurrence
// out of LDS (must replicate reference's per-step rounding exactly); cc/marks
// written to LDS then flushed coalesced. Serial chain = ~4 VALU ops/step.
#define CH 512
__global__ __launch_bounds__(64) void cif_scan_kernel(
    const float* __restrict__ weight_bt, const int* __restrict__ ps_arr,
    float* __restrict__ cc_bt, float4* __restrict__ recs,
    int* __restrict__ nfr, float* __restrict__ out_q, float* __restrict__ out_marks) {
    __shared__ float wsm[CH];
    __shared__ float ccs[CH];
    __shared__ float mks[CH];
    const int b = blockIdx.x, l = threadIdx.x;
    const int ps = ps_arr[b];
    const float* wrow = weight_bt + (size_t)b * TT;

    // persistent scalar state (lane 0's registers survive across chunks)
    float prev_w = 0.f, qsum = 0.f, fc = 0.f;
    int m = 0, t_first = 0;

    for (int t0 = 0; t0 < TT; t0 += CH) {
        // stage chunk: 64 lanes x 8 floats = 512
        *(float4*)&wsm[l * 8]     = *(const float4*)&wrow[t0 + l * 8];
        *(float4*)&wsm[l * 8 + 4] = *(const float4*)&wrow[t0 + l * 8 + 4];
        __syncthreads();
        if (l == 0) {
            for (int i = 0; i < CH; ++i) {
                const int t = t0 + i;
                const float w = wsm[i];
                qsum += w;
                if (t == 0) fc = w;
                float mark = 0.f;
                const bool fired = (prev_w + w >= 1.0f);
                const float remained = 1.0f - prev_w;
                if (fired) {
                    ccs[i] = remained;
                    recs[b * TT + m] = make_float4(__int_as_float(t_first), __int_as_float(t), fc, 1.0f);
                    mark = 1.f;
                    ++m;
                    t_first = t;
                    fc = w - remained;
                    prev_w = w - remained;
                } else {
                    ccs[i] = w;
                    prev_w += w;
                }
                if (t == ps && prev_w > 0.6f) {
                    recs[b * TT + m] = make_float4(__int_as_float(t_first), __int_as_float(t - 1),
                                                   fc, 1.0f / (prev_w + 1e-10f));
                    mark = 1.f;
                    ++m;
                }
                mks[i] = mark;
            }
        }
        __syncthreads();
        // flush chunk coalesced
        *(float4*)&cc_bt[(size_t)b * TT + t0 + l * 8]     = *(const float4*)&ccs[l * 8];
        *(float4*)&cc_bt[(size_t)b * TT + t0 + l * 8 + 4] = *(const float4*)&ccs[l * 8 + 4];
        *(float4*)&out_marks[(size_t)b * TT + t0 + l * 8]     = *(const float4*)&mks[l * 8];
        *(float4*)&out_marks[(size_t)b * TT + t0 + l * 8 + 4] = *(const float4*)&mks[l * 8 + 4];
        __syncthreads();
    }
    if (l == 0) { out_q[b] = qsum; nfr[b] = m; }
}

// ---------------------------------------------------------------------------
// Parallel frame materialization: block (j, b) -> compacted slot j of batch b.
// frame = scale * sum_t coeff(t) * x[t, b, :], short window (typ. 2-4 steps).
__global__ __launch_bounds__(128) void cif_out_kernel(
    const float* __restrict__ x, const float* __restrict__ cc_bt,
    const float4* __restrict__ recs, const int* __restrict__ nfr,
    float* __restrict__ out_cif, float* __restrict__ out_mask) {
    const int j = blockIdx.x, b = blockIdx.y;
    const int l = threadIdx.x;
    const int m = nfr[b];
    float4 acc = make_float4(0.f, 0.f, 0.f, 0.f);
    const size_t obase = ((size_t)b * TT + j) * EE + l * 4;
    if (j < m) {
        const float4 r = recs[b * TT + j];
        const int t0 = __float_as_int(r.x);
        const int t1 = __float_as_int(r.y);
        const float fcoef = r.z, scale = r.w;
        for (int t = t0; t <= t1; ++t) {
            const float coeff = (t == t0) ? fcoef : cc_bt[(size_t)b * TT + t];
            const float4 xv = *(const float4*)&x[((size_t)t * BB + b) * EE + l * 4];
            acc.x = fmaf(coeff, xv.x, acc.x);
            acc.y = fmaf(coeff, xv.y, acc.y);
            acc.z = fmaf(coeff, xv.z, acc.z);
            acc.w = fmaf(coeff, xv.w, acc.w);
        }
        acc.x *= scale; acc.y *= scale; acc.z *= scale; acc.w *= scale;
        if (l == 0) out_mask[b * TT + j] = 1.f;
    } else {
        if (l == 0) out_mask[b * TT + j] = 0.f;
    }
    *(float4*)&out_cif[obase] = acc;
}

// ---------------------------------------------------------------------------
extern "C" void kernel_launch(void* const* d_in, const int* in_sizes, int n_in,
                              void* d_out, int out_size, void* d_ws, size_t ws_size,
                              hipStream_t stream) {
    const float* x    = (const float*)d_in[0];   // (T, B, E)
    const void*  pm   = d_in[1];                 // (B, T) bool -> int32 or bytes (detected)
    const float* W    = (const float*)d_in[2];   // (E, N)
    const float* bias = (const float*)d_in[3];   // (N,)
    const float* v    = (const float*)d_in[4];   // (N, 1)
    const float* vb   = (const float*)d_in[5];   // (1,)

    float* ws       = (float*)d_ws;
    float* weight_bt = ws;                                 // BB*TT
    float* cc_bt     = ws + TT * BB;                       // BB*TT
    float4* recs     = (float4*)(ws + 2 * TT * BB);        // BB*TT float4
    int* nfr         = (int*)(ws + 2 * TT * BB + 4 * BB * TT);
    int* ps          = nfr + BB;
    int* flag        = ps + BB;

    float* out_cif   = (float*)d_out;                     // (B, T, E)
    float* out_mask  = out_cif + (size_t)BB * TT * EE;    // (B, T)
    float* out_q     = out_mask + (size_t)BB * TT;        // (B,)
    float* out_marks = out_q + BB;                        // (B, T)

    detect_mask_kernel<<<1, 256, 0, stream>>>((const unsigned*)pm, flag);
    compute_ps_kernel<<<BB, 256, 0, stream>>>(pm, flag, ps);
    gemm_weight_kernel<<<TT, 256, 0, stream>>>(x, pm, flag, W, bias, v, vb, weight_bt);
    cif_scan_kernel<<<BB, 64, 0, stream>>>(weight_bt, ps, cc_bt, recs, nfr, out_q, out_marks);
    cif_out_kernel<<<dim3(TT, BB), 128, 0, stream>>>(x, cc_bt, recs, nfr, out_cif, out_mask);
}

// Round 3
// 917.014 us; speedup vs baseline: 1.6665x; 1.1692x over previous
//
#include <hip/hip_runtime.h>
#include <math.h>

#define TT 2048
#define BB 32
#define EE 512
#define NN 512

// ---------------------------------------------------------------------------
// padding_mask dtype detector: int32 0/1 words stay <=1; byte-bool rows are
// monotonic so any packed word is 0x01000000/0x01010000/0x01010101/... (>1).
__global__ void detect_mask_kernel(const unsigned* __restrict__ pm, int* __restrict__ flag) {
    __shared__ int s[256];
    const int l = threadIdx.x;
    int bad = 0;
    for (int i = l; i < BB * TT; i += 256) bad |= (pm[i] > 1u);
    s[l] = bad;
    __syncthreads();
    for (int st = 128; st > 0; st >>= 1) { if (l < st) s[l] |= s[l + st]; __syncthreads(); }
    if (l == 0) *flag = s[0];
}

__device__ __forceinline__ int pad_at(const void* pm, int idx, int isByte) {
    return isByte ? (int)(((const unsigned char*)pm)[idx] != 0)
                  : (int)(((const int*)pm)[idx] != 0);
}

// ---------------------------------------------------------------------------
// padding_start[b] = count of not-pad = lengths[b]
__global__ void compute_ps_kernel(const void* __restrict__ pm, const int* __restrict__ flag,
                                  int* __restrict__ ps) {
    __shared__ int s[256];
    const int b = blockIdx.x, l = threadIdx.x;
    const int isByte = *flag;
    int cnt = 0;
    for (int t = l; t < TT; t += 256) cnt += (pad_at(pm, b * TT + t, isByte) == 0);
    s[l] = cnt;
    __syncthreads();
    for (int st = 128; st > 0; st >>= 1) { if (l < st) s[l] += s[l + st]; __syncthreads(); }
    if (l == 0) ps[b] = s[0];
}

// ---------------------------------------------------------------------------
// Fused fp32 GEMM + relu + dot(v) + sigmoid + mask.
// One block per t (32 rows = all b). BM=32 rows x full N=512, BK=8.
// 256 threads: ty in [0,8) -> 4 rows each; tx in [0,32) owns columns
// n = g*128 + tx*4 + j (strided ownership -> conflict-free Bs reads:
// 32 lanes x float4 span all 32 banks; half-waves broadcast).
__global__ __launch_bounds__(256, 2) void gemm_weight_kernel(
    const float* __restrict__ x, const void* __restrict__ pm, const int* __restrict__ flag,
    const float* __restrict__ W, const float* __restrict__ bias,
    const float* __restrict__ v, const float* __restrict__ vb,
    float* __restrict__ weight_bt) {
    __shared__ float Bs[8][512];
    __shared__ float As[8][36];   // [k][row], padded to 36
    __shared__ float bias_s[512], v_s[512];
    const int l = threadIdx.x;
    const int tx = l & 31, ty = l >> 5;
    const int t = blockIdx.x;
    for (int i = l; i < 512; i += 256) { bias_s[i] = bias[i]; v_s[i] = v[i]; }

    float acc[4][16];
#pragma unroll
    for (int i = 0; i < 4; ++i)
#pragma unroll
        for (int j = 0; j < 16; ++j) acc[i][j] = 0.f;

    const float* xblk = x + (size_t)t * (BB * EE);  // rows r = t*32 + b are contiguous
    const int arow = l >> 3, akk = l & 7;           // 32 rows x 8 k each staged by one lane

    for (int k0 = 0; k0 < EE; k0 += 8) {
        __syncthreads();
        As[akk][arow] = xblk[arow * EE + k0 + akk];
#pragma unroll
        for (int j = 0; j < 4; ++j) {
            const int idx = l + j * 256;     // 0..1023 -> 8 k-rows x 128 float4
            const int kk = idx >> 7, n4 = idx & 127;
            *(float4*)&Bs[kk][n4 * 4] = *(const float4*)&W[(size_t)(k0 + kk) * NN + n4 * 4];
        }
        __syncthreads();
#pragma unroll
        for (int k = 0; k < 8; ++k) {
            const float4 a4 = *(const float4*)&As[k][ty * 4];
            const float4 b0 = *(const float4*)&Bs[k][0 * 128 + tx * 4];
            const float4 b1 = *(const float4*)&Bs[k][1 * 128 + tx * 4];
            const float4 b2 = *(const float4*)&Bs[k][2 * 128 + tx * 4];
            const float4 b3 = *(const float4*)&Bs[k][3 * 128 + tx * 4];
            const float a[4] = {a4.x, a4.y, a4.z, a4.w};
            const float bv[16] = {b0.x, b0.y, b0.z, b0.w, b1.x, b1.y, b1.z, b1.w,
                                  b2.x, b2.y, b2.z, b2.w, b3.x, b3.y, b3.z, b3.w};
#pragma unroll
            for (int i = 0; i < 4; ++i)
#pragma unroll
                for (int j = 0; j < 16; ++j) acc[i][j] = fmaf(a[i], bv[j], acc[i][j]);
        }
    }
    // epilogue: relu, dot with v over this thread's 16 (strided) cols, butterfly over tx
    float rsum[4] = {0.f, 0.f, 0.f, 0.f};
#pragma unroll
    for (int i = 0; i < 4; ++i) {
#pragma unroll
        for (int j = 0; j < 16; ++j) {
            const int n = (j >> 2) * 128 + tx * 4 + (j & 3);
            float h = fmaxf(acc[i][j] + bias_s[n], 0.f);
            rsum[i] = fmaf(h, v_s[n], rsum[i]);
        }
    }
#pragma unroll
    for (int m = 16; m >= 1; m >>= 1) {
#pragma unroll
        for (int i = 0; i < 4; ++i) rsum[i] += __shfl_xor(rsum[i], m, 64);
    }
    if (tx == 0) {
        const int isByte = *flag;
        const float vbias = *vb;
#pragma unroll
        for (int i = 0; i < 4; ++i) {
            const int b = ty * 4 + i;
            const float lg = rsum[i] + vbias;
            const float wg = 1.0f / (1.0f + expf(-lg));
            weight_bt[(size_t)b * TT + t] = pad_at(pm, b * TT + t, isByte) ? 0.f : wg;
        }
    }
}

// ---------------------------------------------------------------------------
// Sequential scalar scan, one block per batch. Weights staged through LDS in
// 512-step chunks; lane 0 runs the serial fp32 recurrence (must replicate
// reference's per-step rounding exactly) with 8-wide register prefetch so
// LDS latency is off the dependent chain.
#define CH 512
__global__ __launch_bounds__(64) void cif_scan_kernel(
    const float* __restrict__ weight_bt, const int* __restrict__ ps_arr,
    float* __restrict__ cc_bt, float4* __restrict__ recs,
    int* __restrict__ nfr, float* __restrict__ out_q, float* __restrict__ out_marks) {
    __shared__ float wsm[CH];
    __shared__ float ccs[CH];
    __shared__ float mks[CH];
    const int b = blockIdx.x, l = threadIdx.x;
    const int ps = ps_arr[b];
    const float* wrow = weight_bt + (size_t)b * TT;

    // persistent scalar state (lane 0's registers survive across chunks)
    float prev_w = 0.f, qsum = 0.f, fc = 0.f;
    int m = 0, t_first = 0;

    for (int t0 = 0; t0 < TT; t0 += CH) {
        // stage chunk: 64 lanes x 8 floats = 512
        *(float4*)&wsm[l * 8]     = *(const float4*)&wrow[t0 + l * 8];
        *(float4*)&wsm[l * 8 + 4] = *(const float4*)&wrow[t0 + l * 8 + 4];
        __syncthreads();
        if (l == 0) {
            for (int i = 0; i < CH; i += 8) {
                const float4 wa = *(const float4*)&wsm[i];
                const float4 wb = *(const float4*)&wsm[i + 4];
                const float wv[8] = {wa.x, wa.y, wa.z, wa.w, wb.x, wb.y, wb.z, wb.w};
#pragma unroll
                for (int u = 0; u < 8; ++u) {
                    const int t = t0 + i + u;
                    const float w = wv[u];
                    qsum += w;
                    if (t == 0) fc = w;
                    float mark = 0.f;
                    const bool fired = (prev_w + w >= 1.0f);
                    const float remained = 1.0f - prev_w;
                    if (fired) {
                        ccs[i + u] = remained;
                        recs[b * TT + m] = make_float4(__int_as_float(t_first), __int_as_float(t), fc, 1.0f);
                        mark = 1.f;
                        ++m;
                        t_first = t;
                        fc = w - remained;
                        prev_w = w - remained;
                    } else {
                        ccs[i + u] = w;
                        prev_w += w;
                    }
                    if (t == ps && prev_w > 0.6f) {
                        recs[b * TT + m] = make_float4(__int_as_float(t_first), __int_as_float(t - 1),
                                                       fc, 1.0f / (prev_w + 1e-10f));
                        mark = 1.f;
                        ++m;
                    }
                    mks[i + u] = mark;
                }
            }
        }
        __syncthreads();
        // flush chunk coalesced
        *(float4*)&cc_bt[(size_t)b * TT + t0 + l * 8]     = *(const float4*)&ccs[l * 8];
        *(float4*)&cc_bt[(size_t)b * TT + t0 + l * 8 + 4] = *(const float4*)&ccs[l * 8 + 4];
        *(float4*)&out_marks[(size_t)b * TT + t0 + l * 8]     = *(const float4*)&mks[l * 8];
        *(float4*)&out_marks[(size_t)b * TT + t0 + l * 8 + 4] = *(const float4*)&mks[l * 8 + 4];
        __syncthreads();
    }
    if (l == 0) { out_q[b] = qsum; nfr[b] = m; }
}

// ---------------------------------------------------------------------------
// Parallel frame materialization: block (j, b) -> compacted slot j of batch b.
// frame = scale * sum_t coeff(t) * x[t, b, :], short window (typ. 2-4 steps).
__global__ __launch_bounds__(128) void cif_out_kernel(
    const float* __restrict__ x, const float* __restrict__ cc_bt,
    const float4* __restrict__ recs, const int* __restrict__ nfr,
    float* __restrict__ out_cif, float* __restrict__ out_mask) {
    const int j = blockIdx.x, b = blockIdx.y;
    const int l = threadIdx.x;
    const int m = nfr[b];
    float4 acc = make_float4(0.f, 0.f, 0.f, 0.f);
    const size_t obase = ((size_t)b * TT + j) * EE + l * 4;
    if (j < m) {
        const float4 r = recs[b * TT + j];
        const int t0 = __float_as_int(r.x);
        const int t1 = __float_as_int(r.y);
        const float fcoef = r.z, scale = r.w;
        for (int t = t0; t <= t1; ++t) {
            const float coeff = (t == t0) ? fcoef : cc_bt[(size_t)b * TT + t];
            const float4 xv = *(const float4*)&x[((size_t)t * BB + b) * EE + l * 4];
            acc.x = fmaf(coeff, xv.x, acc.x);
            acc.y = fmaf(coeff, xv.y, acc.y);
            acc.z = fmaf(coeff, xv.z, acc.z);
            acc.w = fmaf(coeff, xv.w, acc.w);
        }
        acc.x *= scale; acc.y *= scale; acc.z *= scale; acc.w *= scale;
        if (l == 0) out_mask[b * TT + j] = 1.f;
    } else {
        if (l == 0) out_mask[b * TT + j] = 0.f;
    }
    *(float4*)&out_cif[obase] = acc;
}

// ---------------------------------------------------------------------------
extern "C" void kernel_launch(void* const* d_in, const int* in_sizes, int n_in,
                              void* d_out, int out_size, void* d_ws, size_t ws_size,
                              hipStream_t stream) {
    const float* x    = (const float*)d_in[0];   // (T, B, E)
    const void*  pm   = d_in[1];                 // (B, T) bool -> int32 or bytes (detected)
    const float* W    = (const float*)d_in[2];   // (E, N)
    const float* bias = (const float*)d_in[3];   // (N,)
    const float* v    = (const float*)d_in[4];   // (N, 1)
    const float* vb   = (const float*)d_in[5];   // (1,)

    float* ws        = (float*)d_ws;
    float* weight_bt = ws;                                 // BB*TT
    float* cc_bt     = ws + TT * BB;                       // BB*TT
    float4* recs     = (float4*)(ws + 2 * TT * BB);        // BB*TT float4
    int* nfr         = (int*)(ws + 2 * TT * BB + 4 * BB * TT);
    int* ps          = nfr + BB;
    int* flag        = ps + BB;

    float* out_cif   = (float*)d_out;                     // (B, T, E)
    float* out_mask  = out_cif + (size_t)BB * TT * EE;    // (B, T)
    float* out_q     = out_mask + (size_t)BB * TT;        // (B,)
    float* out_marks = out_q + BB;                        // (B, T)

    detect_mask_kernel<<<1, 256, 0, stream>>>((const unsigned*)pm, flag);
    compute_ps_kernel<<<BB, 256, 0, stream>>>(pm, flag, ps);
    gemm_weight_kernel<<<TT, 256, 0, stream>>>(x, pm, flag, W, bias, v, vb, weight_bt);
    cif_scan_kernel<<<BB, 64, 0, stream>>>(weight_bt, ps, cc_bt, recs, nfr, out_q, out_marks);
    cif_out_kernel<<<dim3(TT, BB), 128, 0, stream>>>(x, cc_bt, recs, nfr, out_cif, out_mask);
}

// Round 4
// 870.041 us; speedup vs baseline: 1.7564x; 1.0540x over previous
//
#include <hip/hip_runtime.h>
#include <math.h>

#define TT 2048
#define BB 32
#define EE 512
#define NN 512

// ---------------------------------------------------------------------------
// padding_mask dtype detector: int32 0/1 words stay <=1; byte-bool rows are
// monotonic so any packed word is 0x01000000/0x01010000/0x01010101/... (>1).
__global__ void detect_mask_kernel(const unsigned* __restrict__ pm, int* __restrict__ flag) {
    __shared__ int s[1024];
    const int l = threadIdx.x;
    int bad = 0;
    for (int i = l; i < BB * TT; i += 1024) bad |= (pm[i] > 1u);
    s[l] = bad;
    __syncthreads();
    for (int st = 512; st > 0; st >>= 1) { if (l < st) s[l] |= s[l + st]; __syncthreads(); }
    if (l == 0) *flag = s[0];
}

__device__ __forceinline__ int pad_at(const void* pm, int idx, int isByte) {
    return isByte ? (int)(((const unsigned char*)pm)[idx] != 0)
                  : (int)(((const int*)pm)[idx] != 0);
}

// ---------------------------------------------------------------------------
// padding_start[b] = count of not-pad = lengths[b]
__global__ void compute_ps_kernel(const void* __restrict__ pm, const int* __restrict__ flag,
                                  int* __restrict__ ps) {
    __shared__ int s[256];
    const int b = blockIdx.x, l = threadIdx.x;
    const int isByte = *flag;
    int cnt = 0;
    for (int t = l; t < TT; t += 256) cnt += (pad_at(pm, b * TT + t, isByte) == 0);
    s[l] = cnt;
    __syncthreads();
    for (int st = 128; st > 0; st >>= 1) { if (l < st) s[l] += s[l + st]; __syncthreads(); }
    if (l == 0) ps[b] = s[0];
}

// ---------------------------------------------------------------------------
// Fused fp32 GEMM + relu + dot(v) + sigmoid + mask.
// One block per 2 t-values: 64 rows x N=512, BK=8, 1024 blocks.
// 256 threads: ty in [0,8) -> 8 rows each; tx in [0,32) owns cols
// n = g*128 + tx*4 + j (conflict-free strided Bs reads, half-wave broadcast).
// Per k: 6 ds_read_b128 feed 128 FMA-instr (LDS ratio 0.56 cyc/FMA-inst).
__global__ __launch_bounds__(256, 2) void gemm_weight_kernel(
    const float* __restrict__ x, const void* __restrict__ pm, const int* __restrict__ flag,
    const float* __restrict__ W, const float* __restrict__ bias,
    const float* __restrict__ v, const float* __restrict__ vb,
    float* __restrict__ weight_bt) {
    __shared__ float Bs[8][512];
    __shared__ float As[8][72];   // [k][row 0..63], padded to 72
    __shared__ float bias_s[512], v_s[512];
    const int l = threadIdx.x;
    const int tx = l & 31, ty = l >> 5;
    const int tp = blockIdx.x;                       // row block: rows tp*64 .. tp*64+63
    for (int i = l; i < 512; i += 256) { bias_s[i] = bias[i]; v_s[i] = v[i]; }

    float acc[8][16];
#pragma unroll
    for (int i = 0; i < 8; ++i)
#pragma unroll
        for (int j = 0; j < 16; ++j) acc[i][j] = 0.f;

    const float* xblk = x + (size_t)tp * (64 * EE);  // 64 contiguous rows of x

    for (int k0 = 0; k0 < EE; k0 += 8) {
        __syncthreads();
#pragma unroll
        for (int j = 0; j < 2; ++j) {                // stage A: 64 rows x 8 k
            const int idx = l + j * 256;             // 0..511
            const int row = idx >> 3, kk = idx & 7;
            As[kk][row] = xblk[row * EE + k0 + kk];
        }
#pragma unroll
        for (int j = 0; j < 4; ++j) {                // stage B: 8 k x 512 n
            const int idx = l + j * 256;             // 0..1023 -> 8 k x 128 float4
            const int kk = idx >> 7, n4 = idx & 127;
            *(float4*)&Bs[kk][n4 * 4] = *(const float4*)&W[(size_t)(k0 + kk) * NN + n4 * 4];
        }
        __syncthreads();
#pragma unroll
        for (int k = 0; k < 8; ++k) {
            const float4 a0 = *(const float4*)&As[k][ty * 8];
            const float4 a1 = *(const float4*)&As[k][ty * 8 + 4];
            const float4 b0 = *(const float4*)&Bs[k][0 * 128 + tx * 4];
            const float4 b1 = *(const float4*)&Bs[k][1 * 128 + tx * 4];
            const float4 b2 = *(const float4*)&Bs[k][2 * 128 + tx * 4];
            const float4 b3 = *(const float4*)&Bs[k][3 * 128 + tx * 4];
            const float a[8] = {a0.x, a0.y, a0.z, a0.w, a1.x, a1.y, a1.z, a1.w};
            const float bv[16] = {b0.x, b0.y, b0.z, b0.w, b1.x, b1.y, b1.z, b1.w,
                                  b2.x, b2.y, b2.z, b2.w, b3.x, b3.y, b3.z, b3.w};
#pragma unroll
            for (int i = 0; i < 8; ++i)
#pragma unroll
                for (int j = 0; j < 16; ++j) acc[i][j] = fmaf(a[i], bv[j], acc[i][j]);
        }
    }
    // epilogue: relu, dot with v over this thread's 16 (strided) cols, butterfly over tx
    float rsum[8];
#pragma unroll
    for (int i = 0; i < 8; ++i) {
        rsum[i] = 0.f;
#pragma unroll
        for (int j = 0; j < 16; ++j) {
            const int n = (j >> 2) * 128 + tx * 4 + (j & 3);
            float h = fmaxf(acc[i][j] + bias_s[n], 0.f);
            rsum[i] = fmaf(h, v_s[n], rsum[i]);
        }
    }
#pragma unroll
    for (int m = 16; m >= 1; m >>= 1) {
#pragma unroll
        for (int i = 0; i < 8; ++i) rsum[i] += __shfl_xor(rsum[i], m, 64);
    }
    if (tx == 0) {
        const int isByte = *flag;
        const float vbias = *vb;
#pragma unroll
        for (int i = 0; i < 8; ++i) {
            const int r = tp * 64 + ty * 8 + i;      // global row = t*32 + b
            const int t = r >> 5, b = r & 31;
            const float lg = rsum[i] + vbias;
            const float wg = 1.0f / (1.0f + expf(-lg));
            weight_bt[(size_t)b * TT + t] = pad_at(pm, b * TT + t, isByte) ? 0.f : wg;
        }
    }
}

// ---------------------------------------------------------------------------
// Sequential scalar scan, one block per batch. Weights staged through LDS in
// 512-step chunks; lane 0 runs the serial fp32 recurrence (replicates the
// reference's per-step rounding exactly). recs accumulate in LDS (no scattered
// global stores on the dependent chain); qsum reduced in parallel by all lanes.
#define CH 512
#define MAXREC 2080
__global__ __launch_bounds__(64) void cif_scan_kernel(
    const float* __restrict__ weight_bt, const int* __restrict__ ps_arr,
    float* __restrict__ cc_bt, float4* __restrict__ recs,
    int* __restrict__ nfr, float* __restrict__ out_q, float* __restrict__ out_marks) {
    __shared__ float wsm[CH];
    __shared__ float ccs[CH];
    __shared__ float mks[CH];
    __shared__ float4 recs_s[MAXREC];
    __shared__ int m_sh;
    const int b = blockIdx.x, l = threadIdx.x;
    const int ps = ps_arr[b];
    const float* wrow = weight_bt + (size_t)b * TT;

    // persistent scalar state (lane 0's registers survive across chunks)
    float prev_w = 0.f, fc = 0.f;
    int m = 0, t_first = 0;
    float qpart = 0.f;   // per-lane partial of sum(w)

    for (int t0 = 0; t0 < TT; t0 += CH) {
        // stage chunk: 64 lanes x 8 floats = 512
        const float4 la = *(const float4*)&wrow[t0 + l * 8];
        const float4 lb = *(const float4*)&wrow[t0 + l * 8 + 4];
        *(float4*)&wsm[l * 8]     = la;
        *(float4*)&wsm[l * 8 + 4] = lb;
        qpart += la.x + la.y + la.z + la.w + lb.x + lb.y + lb.z + lb.w;
        __syncthreads();
        if (l == 0) {
            for (int i = 0; i < CH; i += 8) {
                const float4 wa = *(const float4*)&wsm[i];
                const float4 wb = *(const float4*)&wsm[i + 4];
                const float wv[8] = {wa.x, wa.y, wa.z, wa.w, wb.x, wb.y, wb.z, wb.w};
#pragma unroll
                for (int u = 0; u < 8; ++u) {
                    const int t = t0 + i + u;
                    const float w = wv[u];
                    if (t == 0) fc = w;
                    float mark = 0.f;
                    const bool fired = (prev_w + w >= 1.0f);
                    const float remained = 1.0f - prev_w;
                    if (fired) {
                        ccs[i + u] = remained;
                        recs_s[m] = make_float4(__int_as_float(t_first), __int_as_float(t), fc, 1.0f);
                        mark = 1.f;
                        ++m;
                        t_first = t;
                        fc = w - remained;
                        prev_w = w - remained;
                    } else {
                        ccs[i + u] = w;
                        prev_w += w;
                    }
                    if (t == ps && prev_w > 0.6f) {
                        recs_s[m] = make_float4(__int_as_float(t_first), __int_as_float(t - 1),
                                                fc, 1.0f / (prev_w + 1e-10f));
                        mark = 1.f;
                        ++m;
                    }
                    mks[i + u] = mark;
                }
            }
            m_sh = m;
        }
        __syncthreads();
        // flush chunk coalesced
        *(float4*)&cc_bt[(size_t)b * TT + t0 + l * 8]     = *(const float4*)&ccs[l * 8];
        *(float4*)&cc_bt[(size_t)b * TT + t0 + l * 8 + 4] = *(const float4*)&ccs[l * 8 + 4];
        *(float4*)&out_marks[(size_t)b * TT + t0 + l * 8]     = *(const float4*)&mks[l * 8];
        *(float4*)&out_marks[(size_t)b * TT + t0 + l * 8 + 4] = *(const float4*)&mks[l * 8 + 4];
        __syncthreads();
    }
    // flush recs coalesced
    const int mtot = m_sh;
    for (int j = l; j < mtot; j += 64) recs[b * TT + j] = recs_s[j];
    // qsum reduction
#pragma unroll
    for (int s = 32; s >= 1; s >>= 1) qpart += __shfl_xor(qpart, s, 64);
    if (l == 0) { out_q[b] = qpart; nfr[b] = mtot; }
}

// ---------------------------------------------------------------------------
// Parallel frame materialization: block (j, b) -> compacted slot j of batch b.
// frame = scale * sum_t coeff(t) * x[t, b, :], short window (typ. 2-4 steps).
__global__ __launch_bounds__(128) void cif_out_kernel(
    const float* __restrict__ x, const float* __restrict__ cc_bt,
    const float4* __restrict__ recs, const int* __restrict__ nfr,
    float* __restrict__ out_cif, float* __restrict__ out_mask) {
    const int j = blockIdx.x, b = blockIdx.y;
    const int l = threadIdx.x;
    const int m = nfr[b];
    float4 acc = make_float4(0.f, 0.f, 0.f, 0.f);
    const size_t obase = ((size_t)b * TT + j) * EE + l * 4;
    if (j < m) {
        const float4 r = recs[b * TT + j];
        const int t0 = __float_as_int(r.x);
        const int t1 = __float_as_int(r.y);
        const float fcoef = r.z, scale = r.w;
        for (int t = t0; t <= t1; ++t) {
            const float coeff = (t == t0) ? fcoef : cc_bt[(size_t)b * TT + t];
            const float4 xv = *(const float4*)&x[((size_t)t * BB + b) * EE + l * 4];
            acc.x = fmaf(coeff, xv.x, acc.x);
            acc.y = fmaf(coeff, xv.y, acc.y);
            acc.z = fmaf(coeff, xv.z, acc.z);
            acc.w = fmaf(coeff, xv.w, acc.w);
        }
        acc.x *= scale; acc.y *= scale; acc.z *= scale; acc.w *= scale;
        if (l == 0) out_mask[b * TT + j] = 1.f;
    } else {
        if (l == 0) out_mask[b * TT + j] = 0.f;
    }
    *(float4*)&out_cif[obase] = acc;
}

// ---------------------------------------------------------------------------
extern "C" void kernel_launch(void* const* d_in, const int* in_sizes, int n_in,
                              void* d_out, int out_size, void* d_ws, size_t ws_size,
                              hipStream_t stream) {
    const float* x    = (const float*)d_in[0];   // (T, B, E)
    const void*  pm   = d_in[1];                 // (B, T) bool -> int32 or bytes (detected)
    const float* W    = (const float*)d_in[2];   // (E, N)
    const float* bias = (const float*)d_in[3];   // (N,)
    const float* v    = (const float*)d_in[4];   // (N, 1)
    const float* vb   = (const float*)d_in[5];   // (1,)

    float* ws        = (float*)d_ws;
    float* weight_bt = ws;                                 // BB*TT
    float* cc_bt     = ws + TT * BB;                       // BB*TT
    float4* recs     = (float4*)(ws + 2 * TT * BB);        // BB*TT float4
    int* nfr         = (int*)(ws + 2 * TT * BB + 4 * BB * TT);
    int* ps          = nfr + BB;
    int* flag        = ps + BB;

    float* out_cif   = (float*)d_out;                     // (B, T, E)
    float* out_mask  = out_cif + (size_t)BB * TT * EE;    // (B, T)
    float* out_q     = out_mask + (size_t)BB * TT;        // (B,)
    float* out_marks = out_q + BB;                        // (B, T)

    detect_mask_kernel<<<1, 1024, 0, stream>>>((const unsigned*)pm, flag);
    compute_ps_kernel<<<BB, 256, 0, stream>>>(pm, flag, ps);
    gemm_weight_kernel<<<TT / 2, 256, 0, stream>>>(x, pm, flag, W, bias, v, vb, weight_bt);
    cif_scan_kernel<<<BB, 64, 0, stream>>>(weight_bt, ps, cc_bt, recs, nfr, out_q, out_marks);
    cif_out_kernel<<<dim3(TT, BB), 128, 0, stream>>>(x, cc_bt, recs, nfr, out_cif, out_mask);
}